// Round 4
// baseline (509.565 us; speedup 1.0000x reference)
//
#include <hip/hip_runtime.h>
#include <math.h>

#define BB 16
#define SS 4096
#define HH 1024
#define CC 64

typedef __attribute__((ext_vector_type(4))) float f32x4;
typedef __attribute__((ext_vector_type(8))) short s16x8;

__device__ __forceinline__ ushort f2bf(float x) {
    union { float f; unsigned u; } un; un.f = x;
    unsigned r = (un.u + 0x7FFFu + ((un.u >> 16) & 1u)) >> 16;
    return (ushort)r;
}
__device__ __forceinline__ float bf2f(ushort h) {
    union { unsigned u; float f; } un; un.u = ((unsigned)h) << 16; return un.f;
}

// ---------------- prep: querys -> hi/lo bf16
__global__ __launch_bounds__(256) void prep_querys_kernel(
    const float* __restrict__ q, ushort* __restrict__ qhi, ushort* __restrict__ qlo)
{
    const int i4 = blockIdx.x * 256 + threadIdx.x;   // float4 index, 16384 total
    const float4 v = ((const float4*)q)[i4];
    ushort4 h, l;
    h.x = f2bf(v.x); l.x = f2bf(v.x - bf2f(h.x));
    h.y = f2bf(v.y); l.y = f2bf(v.y - bf2f(h.y));
    h.z = f2bf(v.z); l.z = f2bf(v.z - bf2f(h.z));
    h.w = f2bf(v.w); l.w = f2bf(v.w - bf2f(h.w));
    ((ushort4*)qhi)[i4] = h;
    ((ushort4*)qlo)[i4] = l;
}

// ---------------- scores: LDS-free, deep register pipeline.
// A (hidden, HBM): depth-2 prefetch via 3-slot ring. B-hi (L2): depth-1.
// B-lo: loaded in-iter, consumed after 8 MFMAs. Full k-unroll -> static slots.
__global__ __launch_bounds__(256, 4) void scores_kernel(
    const float* __restrict__ hidden, const ushort* __restrict__ qhi,
    const ushort* __restrict__ qlo, float* __restrict__ scores)
{
    const int b = blockIdx.y, t = threadIdx.x;
    const int w = t >> 6, lane = t & 63, col = lane & 15, quad = lane >> 4;
    const int s0 = blockIdx.x * 64 + w * 16;

    const float*  arow = hidden + ((size_t)b * SS + s0 + col) * HH + quad * 8;
    const ushort* qh0  = qhi + (size_t)col * HH + quad * 8;
    const ushort* ql0  = qlo + (size_t)col * HH + quad * 8;

    f32x4 acc[4];
#pragma unroll
    for (int nt = 0; nt < 4; ++nt) acc[nt] = (f32x4){0.f, 0.f, 0.f, 0.f};

    float4 aR[3][2];
    aR[0][0] = *(const float4*)(arow + 0);
    aR[0][1] = *(const float4*)(arow + 4);
    aR[1][0] = *(const float4*)(arow + 32);
    aR[1][1] = *(const float4*)(arow + 36);

    s16x8 bhR[2][4];
#pragma unroll
    for (int nt = 0; nt < 4; ++nt)
        bhR[0][nt] = *(const s16x8*)(qh0 + (size_t)nt * 16 * HH);

#pragma unroll
    for (int kk = 0; kk < 32; ++kk) {
        const int k0 = kk * 32;
        const int ca = kk % 3;
        const int cb = kk & 1;

        s16x8 bl[4];
#pragma unroll
        for (int nt = 0; nt < 4; ++nt)
            bl[nt] = *(const s16x8*)(ql0 + (size_t)nt * 16 * HH + k0);

        if (kk + 1 < 32) {
#pragma unroll
            for (int nt = 0; nt < 4; ++nt)
                bhR[cb ^ 1][nt] = *(const s16x8*)(qh0 + (size_t)nt * 16 * HH + k0 + 32);
        }
        if (kk + 2 < 32) {
            aR[(kk + 2) % 3][0] = *(const float4*)(arow + k0 + 64);
            aR[(kk + 2) % 3][1] = *(const float4*)(arow + k0 + 68);
        }

        const float af[8] = {aR[ca][0].x, aR[ca][0].y, aR[ca][0].z, aR[ca][0].w,
                             aR[ca][1].x, aR[ca][1].y, aR[ca][1].z, aR[ca][1].w};
        s16x8 ah, al;
#pragma unroll
        for (int j = 0; j < 8; ++j) {
            const ushort h = f2bf(af[j]);
            ah[j] = (short)h;
            al[j] = (short)f2bf(af[j] - bf2f(h));
        }
        // hh and lh first (bh already resident), hl last (bl just loaded)
#pragma unroll
        for (int nt = 0; nt < 4; ++nt)
            acc[nt] = __builtin_amdgcn_mfma_f32_16x16x32_bf16(ah, bhR[cb][nt], acc[nt], 0, 0, 0);
#pragma unroll
        for (int nt = 0; nt < 4; ++nt)
            acc[nt] = __builtin_amdgcn_mfma_f32_16x16x32_bf16(al, bhR[cb][nt], acc[nt], 0, 0, 0);
#pragma unroll
        for (int nt = 0; nt < 4; ++nt)
            acc[nt] = __builtin_amdgcn_mfma_f32_16x16x32_bf16(ah, bl[nt], acc[nt], 0, 0, 0);
    }

    // C/D: n(col)=c within n-tile, m(quad*4+reg)=s within this wave's 16-row tile
#pragma unroll
    for (int nt = 0; nt < 4; ++nt) {
        const int c = nt * 16 + col;
        *(f32x4*)&scores[((size_t)(b * CC + c)) * SS + s0 + quad * 4] = acc[nt];
    }
}

// ---------------- softmax over s, writes bf16 factor
__global__ __launch_bounds__(256) void softmax_kernel(
    const float* __restrict__ scores, ushort* __restrict__ factor)
{
    const float* p = scores + (size_t)blockIdx.x * SS;
    ushort* f = factor + (size_t)blockIdx.x * SS;
    const int t = threadIdx.x;
    float4 v[4];
    float m = -3.0e38f;
#pragma unroll
    for (int i = 0; i < 4; ++i) {
        v[i] = *(const float4*)&p[t * 4 + i * 1024];
        m = fmaxf(m, fmaxf(fmaxf(v[i].x, v[i].y), fmaxf(v[i].z, v[i].w)));
    }
#pragma unroll
    for (int off = 1; off < 64; off <<= 1) m = fmaxf(m, __shfl_xor(m, off));
    __shared__ float redm[4];
    __shared__ float reds[4];
    const int wave = t >> 6, lane = t & 63;
    if (lane == 0) redm[wave] = m;
    __syncthreads();
    m = fmaxf(fmaxf(redm[0], redm[1]), fmaxf(redm[2], redm[3]));

    float sum = 0.0f;
#pragma unroll
    for (int i = 0; i < 4; ++i) {
        v[i].x = __expf(v[i].x - m); v[i].y = __expf(v[i].y - m);
        v[i].z = __expf(v[i].z - m); v[i].w = __expf(v[i].w - m);
        sum += (v[i].x + v[i].y) + (v[i].z + v[i].w);
    }
#pragma unroll
    for (int off = 1; off < 64; off <<= 1) sum += __shfl_xor(sum, off);
    if (lane == 0) reds[wave] = sum;
    __syncthreads();
    sum = (reds[0] + reds[1]) + (reds[2] + reds[3]);
    const float inv = 1.0f / sum;
#pragma unroll
    for (int i = 0; i < 4; ++i) {
        ushort4 o;
        o.x = f2bf(v[i].x * inv); o.y = f2bf(v[i].y * inv);
        o.z = f2bf(v[i].z * inv); o.w = f2bf(v[i].w * inv);
        ((ushort4*)f)[t + i * 256] = o;
    }
}

// ---------------- pool: parts[ks][b][c][h] via bf16 MFMA, 64c x 64h tile, split-8 over S.
// Coalesced float4 hidden loads -> bf16 transpose into LDS via ds_write_b16.
#define KSPLIT 8
__global__ __launch_bounds__(256) void pool_kernel(
    const float* __restrict__ hidden, const ushort* __restrict__ factor,
    float* __restrict__ parts)
{
    __shared__ __align__(16) ushort Ht[64][72];  // [h][s], s contiguous

    const int b  = blockIdx.y;
    const int h0 = blockIdx.x * 64;
    const int ks = blockIdx.z;
    const int sbeg = ks * (SS / KSPLIT);
    const int t = threadIdx.x;
    const int w = t >> 6, lane = t & 63, col = lane & 15, quad = lane >> 4;
    const int srow = t >> 2;   // 0..63 (s within chunk)
    const int hq   = t & 3;    // h quad-group

    f32x4 acc[4];
#pragma unroll
    for (int j = 0; j < 4; ++j) acc[j] = (f32x4){0.f, 0.f, 0.f, 0.f};

    const float*  hsrc  = hidden + (size_t)b * SS * HH + h0 + hq * 4;
    const ushort* fbase = factor + (size_t)(b * CC + w * 16 + col) * SS + sbeg;

    float4 g[4];
#pragma unroll
    for (int j = 0; j < 4; ++j)
        g[j] = *(const float4*)&hsrc[(size_t)(sbeg + srow) * HH + j * 16];

    for (int sc = 0; sc < SS / KSPLIT; sc += 64) {
        __syncthreads();
#pragma unroll
        for (int j = 0; j < 4; ++j) {
            const int h = hq * 4 + j * 16;
            Ht[h + 0][srow] = f2bf(g[j].x);
            Ht[h + 1][srow] = f2bf(g[j].y);
            Ht[h + 2][srow] = f2bf(g[j].z);
            Ht[h + 3][srow] = f2bf(g[j].w);
        }
        __syncthreads();

        if (sc + 64 < SS / KSPLIT) {
#pragma unroll
            for (int j = 0; j < 4; ++j)
                g[j] = *(const float4*)&hsrc[(size_t)(sbeg + sc + 64 + srow) * HH + j * 16];
        }

        const s16x8 fa0 = *(const s16x8*)&fbase[sc + quad * 8];
        const s16x8 fa1 = *(const s16x8*)&fbase[sc + 32 + quad * 8];

#pragma unroll
        for (int ksp = 0; ksp < 2; ++ksp) {
            const s16x8 fa = ksp ? fa1 : fa0;
#pragma unroll
            for (int nt = 0; nt < 4; ++nt) {
                const s16x8 hb = *(const s16x8*)&Ht[nt * 16 + col][ksp * 32 + quad * 8];
                acc[nt] = __builtin_amdgcn_mfma_f32_16x16x32_bf16(fa, hb, acc[nt], 0, 0, 0);
            }
        }
    }

    float* dst = parts + (size_t)ks * (BB * CC * HH) + (size_t)b * (CC * HH);
#pragma unroll
    for (int nt = 0; nt < 4; ++nt) {
        const int h = h0 + nt * 16 + col;
#pragma unroll
        for (int r = 0; r < 4; ++r) {
            const int c = w * 16 + quad * 4 + r;
            dst[(size_t)c * HH + h] = acc[nt][r];
        }
    }
}

// ---------------- final reduce of 8 split-K partials
__global__ __launch_bounds__(256) void reduce8_kernel(
    const float* __restrict__ parts, float* __restrict__ out)
{
    const int i = blockIdx.x * 256 + threadIdx.x;   // float4 index, 262144 total
    const float4* p = (const float4*)parts;
    float4 r = {0.f, 0.f, 0.f, 0.f};
#pragma unroll
    for (int j = 0; j < KSPLIT; ++j) {
        const float4 a = p[i + (size_t)j * 262144];
        r.x += a.x; r.y += a.y; r.z += a.z; r.w += a.w;
    }
    ((float4*)out)[i] = r;
}

extern "C" void kernel_launch(void* const* d_in, const int* in_sizes, int n_in,
                              void* d_out, int out_size, void* d_ws, size_t ws_size,
                              hipStream_t stream)
{
    const float* hidden = (const float*)d_in[0];   // [16,4096,1024] fp32
    const float* querys = (const float*)d_in[1];   // [64,1024] fp32
    float* out = (float*)d_out;

    float*  scores = (float*)d_ws;                           // 16 MiB [0,16M)
    ushort* factor = (ushort*)((char*)d_ws + (16u << 20));   // 8 MiB [16M,24M)
    ushort* qhi    = (ushort*)((char*)d_ws + (24u << 20));   // 128 KiB
    ushort* qlo    = qhi + CC * HH;                          // 128 KiB
    float*  parts  = (float*)((char*)d_ws + (32u << 20));    // 32 MiB [32M,64M)

    prep_querys_kernel<<<dim3(CC * HH / 1024), 256, 0, stream>>>(querys, qhi, qlo);
    scores_kernel<<<dim3(SS / 64, BB), 256, 0, stream>>>(hidden, qhi, qlo, scores);
    softmax_kernel<<<dim3(BB * CC), 256, 0, stream>>>(scores, factor);
    pool_kernel<<<dim3(HH / 64, BB, KSPLIT), 256, 0, stream>>>(hidden, factor, parts);
    reduce8_kernel<<<dim3(1024), 256, 0, stream>>>(parts, out);
}

// Round 5
// 493.068 us; speedup vs baseline: 1.0335x; 1.0335x over previous
//
#include <hip/hip_runtime.h>
#include <math.h>

#define BB 16
#define SS 4096
#define HH 1024
#define CC 64
#define KSPLIT 8

typedef __attribute__((ext_vector_type(4))) float f32x4;
typedef __attribute__((ext_vector_type(8))) short s16x8;

__device__ __forceinline__ ushort f2bf(float x) {
    union { float f; unsigned u; } un; un.f = x;
    unsigned r = (un.u + 0x7FFFu + ((un.u >> 16) & 1u)) >> 16;
    return (ushort)r;
}
__device__ __forceinline__ float bf2f(ushort h) {
    union { unsigned u; float f; } un; un.u = ((unsigned)h) << 16; return un.f;
}

// async 16B global->LDS (DMA; lds dest = wave-uniform base + lane*16)
__device__ __forceinline__ void gld_lds16(const float* g, float* l) {
    __builtin_amdgcn_global_load_lds(
        (const __attribute__((address_space(1))) void*)g,
        (__attribute__((address_space(3))) void*)l, 16, 0, 0);
}

// Stage a 64-row x 64-float tile (global row stride HH floats) into LDS.
// XOR swizzle: phys 16B-block p of row r holds logical block p ^ (r&7).
__device__ __forceinline__ void stage64x64(const float* gbase, float* lds, int t) {
    const int w = t >> 6;
    const int L = t & 63;
    const int rsub = L >> 4;      // 0..3
    const int p = L & 15;         // phys block this lane writes
#pragma unroll
    for (int i = 0; i < 4; ++i) {
        const int row = i * 16 + w * 4 + rsub;
        const int kblk = p ^ (row & 7);
        gld_lds16(gbase + (size_t)row * HH + kblk * 4,
                  lds + (size_t)(i * 16 + w * 4) * 64);
    }
}

// ---------------- prep: querys -> hi/lo bf16
__global__ __launch_bounds__(256) void prep_querys_kernel(
    const float* __restrict__ q, ushort* __restrict__ qhi, ushort* __restrict__ qlo)
{
    const int i4 = blockIdx.x * 256 + threadIdx.x;
    const float4 v = ((const float4*)q)[i4];
    ushort4 h, l;
    h.x = f2bf(v.x); l.x = f2bf(v.x - bf2f(h.x));
    h.y = f2bf(v.y); l.y = f2bf(v.y - bf2f(h.y));
    h.z = f2bf(v.z); l.z = f2bf(v.z - bf2f(h.z));
    h.w = f2bf(v.w); l.w = f2bf(v.w - bf2f(h.w));
    ((ushort4*)qhi)[i4] = h;
    ((ushort4*)qlo)[i4] = l;
}

// ---------------- scores: m97-style. 64s x 64c tile, BK=64 fp32 via global_load_lds,
// double-buffered, 1 barrier/chunk. Convert-on-read -> split-bf16 3-product MFMA.
__global__ __launch_bounds__(256, 4) void scores_kernel(
    const float* __restrict__ hidden, const ushort* __restrict__ qhi,
    const ushort* __restrict__ qlo, float* __restrict__ scores)
{
    __shared__ float Abuf[2][64 * 64];   // 32 KB

    const int b = blockIdx.y, t = threadIdx.x;
    const int w = t >> 6, lane = t & 63, col = lane & 15, quad = lane >> 4;
    const int s0 = blockIdx.x * 64;

    f32x4 acc[4];
#pragma unroll
    for (int nt = 0; nt < 4; ++nt) acc[nt] = (f32x4){0.f, 0.f, 0.f, 0.f};

    const float* gA = hidden + ((size_t)b * SS + s0) * HH;
    stage64x64(gA, Abuf[0], t);

    const int r  = w * 16 + col;   // m-row in tile
    const int c7 = col & 7;        // == r & 7
    const ushort* qh0 = qhi + (size_t)col * HH + quad * 8;
    const ushort* ql0 = qlo + (size_t)col * HH + quad * 8;

    for (int kk = 0; kk < 16; ++kk) {
        __syncthreads();                               // stage[kk] complete
        if (kk + 1 < 16)
            stage64x64(gA + (kk + 1) * 64, Abuf[(kk + 1) & 1], t);
        const float* buf = Abuf[kk & 1] + r * 64;
#pragma unroll
        for (int ks = 0; ks < 2; ++ks) {
            const int kg = kk * 64 + ks * 32;
            s16x8 bh[4], bl[4];
#pragma unroll
            for (int nt = 0; nt < 4; ++nt) {
                bh[nt] = *(const s16x8*)(qh0 + (size_t)nt * 16 * HH + kg);
                bl[nt] = *(const s16x8*)(ql0 + (size_t)nt * 16 * HH + kg);
            }
            const int lb = ks * 8 + quad * 2;
            const float4 f0 = *(const float4*)(buf + ((lb ^ c7) << 2));
            const float4 f1 = *(const float4*)(buf + (((lb + 1) ^ c7) << 2));
            const float af[8] = {f0.x, f0.y, f0.z, f0.w, f1.x, f1.y, f1.z, f1.w};
            s16x8 ah, al;
#pragma unroll
            for (int j = 0; j < 8; ++j) {
                const ushort h = f2bf(af[j]);
                ah[j] = (short)h;
                al[j] = (short)f2bf(af[j] - bf2f(h));
            }
#pragma unroll
            for (int nt = 0; nt < 4; ++nt) {
                acc[nt] = __builtin_amdgcn_mfma_f32_16x16x32_bf16(ah, bh[nt], acc[nt], 0, 0, 0);
                acc[nt] = __builtin_amdgcn_mfma_f32_16x16x32_bf16(al, bh[nt], acc[nt], 0, 0, 0);
                acc[nt] = __builtin_amdgcn_mfma_f32_16x16x32_bf16(ah, bl[nt], acc[nt], 0, 0, 0);
            }
        }
    }
#pragma unroll
    for (int nt = 0; nt < 4; ++nt) {
        const int c = nt * 16 + col;
        *(f32x4*)&scores[((size_t)(b * CC + c)) * SS + s0 + w * 16 + quad * 4] = acc[nt];
    }
}

// ---------------- softmax over s, writes bf16 factor
__global__ __launch_bounds__(256) void softmax_kernel(
    const float* __restrict__ scores, ushort* __restrict__ factor)
{
    const float* p = scores + (size_t)blockIdx.x * SS;
    ushort* f = factor + (size_t)blockIdx.x * SS;
    const int t = threadIdx.x;
    float4 v[4];
    float m = -3.0e38f;
#pragma unroll
    for (int i = 0; i < 4; ++i) {
        v[i] = *(const float4*)&p[t * 4 + i * 1024];
        m = fmaxf(m, fmaxf(fmaxf(v[i].x, v[i].y), fmaxf(v[i].z, v[i].w)));
    }
#pragma unroll
    for (int off = 1; off < 64; off <<= 1) m = fmaxf(m, __shfl_xor(m, off));
    __shared__ float redm[4];
    __shared__ float reds[4];
    const int wave = t >> 6, lane = t & 63;
    if (lane == 0) redm[wave] = m;
    __syncthreads();
    m = fmaxf(fmaxf(redm[0], redm[1]), fmaxf(redm[2], redm[3]));

    float sum = 0.0f;
#pragma unroll
    for (int i = 0; i < 4; ++i) {
        v[i].x = __expf(v[i].x - m); v[i].y = __expf(v[i].y - m);
        v[i].z = __expf(v[i].z - m); v[i].w = __expf(v[i].w - m);
        sum += (v[i].x + v[i].y) + (v[i].z + v[i].w);
    }
#pragma unroll
    for (int off = 1; off < 64; off <<= 1) sum += __shfl_xor(sum, off);
    if (lane == 0) reds[wave] = sum;
    __syncthreads();
    sum = (reds[0] + reds[1]) + (reds[2] + reds[3]);
    const float inv = 1.0f / sum;
#pragma unroll
    for (int i = 0; i < 4; ++i) {
        ushort4 o;
        o.x = f2bf(v[i].x * inv); o.y = f2bf(v[i].y * inv);
        o.z = f2bf(v[i].z * inv); o.w = f2bf(v[i].w * inv);
        ((ushort4*)f)[t + i * 256] = o;
    }
}

// ---------------- pool: staged fp32 tile via global_load_lds + in-LDS transpose
// to bf16 Ht[h][s], software-pipelined. MFMA/store identical to round 4.
__global__ __launch_bounds__(256, 3) void pool_kernel(
    const float* __restrict__ hidden, const ushort* __restrict__ factor,
    float* __restrict__ parts)
{
    __shared__ float Sbuf[2][64 * 64];           // 32 KB
    __shared__ __align__(16) ushort Ht[64][72];  // 9 KB, bf16 [h][s]

    const int b = blockIdx.y, h0 = blockIdx.x * 64, ks = blockIdx.z;
    const int sbeg = ks * (SS / KSPLIT);
    const int t = threadIdx.x;
    const int w = t >> 6, lane = t & 63, col = lane & 15, quad = lane >> 4;
    const int hT = t & 31;     // transpose h (plus 32*u)
    const int sblk = t >> 5;   // 0..7

    f32x4 acc[4];
#pragma unroll
    for (int j = 0; j < 4; ++j) acc[j] = (f32x4){0.f, 0.f, 0.f, 0.f};

    const float*  gH    = hidden + ((size_t)b * SS + sbeg) * HH + h0;
    const ushort* fbase = factor + (size_t)(b * CC + w * 16 + col) * SS + sbeg;

    stage64x64(gH, Sbuf[0], t);

    for (int ci = 0; ci <= 8; ++ci) {
        __syncthreads();                          // stage[ci] done; Ht[ci-1] visible
        if (ci + 1 <= 7)
            stage64x64(gH + (size_t)(ci + 1) * 64 * HH, Sbuf[(ci + 1) & 1], t);

        float vals[16];
        if (ci <= 7) {
            const float* sb = Sbuf[ci & 1];
#pragma unroll
            for (int u = 0; u < 2; ++u) {
                const int h = hT + 32 * u;
#pragma unroll
                for (int i = 0; i < 8; ++i) {
                    const int s = sblk * 8 + i;   // s&7 == i
                    vals[u * 8 + i] = sb[s * 64 + ((((h >> 2) ^ i) << 2) | (h & 3))];
                }
            }
        }
        if (ci >= 1) {
            const int so = (ci - 1) * 64;
            const s16x8 fa0 = *(const s16x8*)&fbase[so + quad * 8];
            const s16x8 fa1 = *(const s16x8*)&fbase[so + 32 + quad * 8];
#pragma unroll
            for (int ksp = 0; ksp < 2; ++ksp) {
                const s16x8 fa = ksp ? fa1 : fa0;
#pragma unroll
                for (int nt = 0; nt < 4; ++nt) {
                    const s16x8 hb = *(const s16x8*)&Ht[nt * 16 + col][ksp * 32 + quad * 8];
                    acc[nt] = __builtin_amdgcn_mfma_f32_16x16x32_bf16(fa, hb, acc[nt], 0, 0, 0);
                }
            }
        }
        __syncthreads();                          // Ht/Sbuf reads done
        if (ci <= 7) {
#pragma unroll
            for (int u = 0; u < 2; ++u) {
                const int h = hT + 32 * u;
                s16x8 pk;
#pragma unroll
                for (int i = 0; i < 8; ++i) pk[i] = (short)f2bf(vals[u * 8 + i]);
                *(s16x8*)&Ht[h][sblk * 8] = pk;
            }
        }
    }

    float* dst = parts + (size_t)ks * (BB * CC * HH) + (size_t)b * (CC * HH);
#pragma unroll
    for (int nt = 0; nt < 4; ++nt) {
        const int h = h0 + nt * 16 + col;
#pragma unroll
        for (int r = 0; r < 4; ++r) {
            const int c = w * 16 + quad * 4 + r;
            dst[(size_t)c * HH + h] = acc[nt][r];
        }
    }
}

// ---------------- final reduce of 8 split-K partials
__global__ __launch_bounds__(256) void reduce8_kernel(
    const float* __restrict__ parts, float* __restrict__ out)
{
    const int i = blockIdx.x * 256 + threadIdx.x;
    const float4* p = (const float4*)parts;
    float4 r = {0.f, 0.f, 0.f, 0.f};
#pragma unroll
    for (int j = 0; j < KSPLIT; ++j) {
        const float4 a = p[i + (size_t)j * 262144];
        r.x += a.x; r.y += a.y; r.z += a.z; r.w += a.w;
    }
    ((float4*)out)[i] = r;
}

extern "C" void kernel_launch(void* const* d_in, const int* in_sizes, int n_in,
                              void* d_out, int out_size, void* d_ws, size_t ws_size,
                              hipStream_t stream)
{
    const float* hidden = (const float*)d_in[0];   // [16,4096,1024] fp32
    const float* querys = (const float*)d_in[1];   // [64,1024] fp32
    float* out = (float*)d_out;

    float*  scores = (float*)d_ws;                           // 16 MiB [0,16M)
    ushort* factor = (ushort*)((char*)d_ws + (16u << 20));   // 8 MiB [16M,24M)
    ushort* qhi    = (ushort*)((char*)d_ws + (24u << 20));   // 128 KiB
    ushort* qlo    = qhi + CC * HH;                          // 128 KiB
    float*  parts  = (float*)((char*)d_ws + (32u << 20));    // 32 MiB [32M,64M)

    prep_querys_kernel<<<dim3(CC * HH / 1024), 256, 0, stream>>>(querys, qhi, qlo);
    scores_kernel<<<dim3(SS / 64, BB), 256, 0, stream>>>(hidden, qhi, qlo, scores);
    softmax_kernel<<<dim3(BB * CC), 256, 0, stream>>>(scores, factor);
    pool_kernel<<<dim3(HH / 64, BB, KSPLIT), 256, 0, stream>>>(hidden, factor, parts);
    reduce8_kernel<<<dim3(1024), 256, 0, stream>>>(parts, out);
}